// Round 1
// baseline (2965.995 us; speedup 1.0000x reference)
//
#include <hip/hip_runtime.h>
#include <hip/hip_cooperative_groups.h>
#include <hip/hip_bf16.h>
#include <stdint.h>

namespace cg = cooperative_groups;

#define TT 128
#define BB 32
#define EE 512
#define HH 1024
#define VV 32000

typedef unsigned short u16;
typedef short bf16x8 __attribute__((ext_vector_type(8)));
typedef float f32x4 __attribute__((ext_vector_type(4)));

__device__ __forceinline__ u16 f2bf(float f) {
    unsigned int u = __builtin_bit_cast(unsigned int, f);
    u = (u + 0x7fffu + ((u >> 16) & 1u)) >> 16;
    return (u16)u;
}

__device__ __forceinline__ void gld_lds16(const u16* g, u16* l) {
    __builtin_amdgcn_global_load_lds(
        (__attribute__((address_space(1))) void*)g,
        (__attribute__((address_space(3))) void*)l, 16, 0, 0);
}

// ---------------- fp32 -> bf16 cast, 4 elems/thread ----------------
__global__ void k_cast(const float* __restrict__ s, u16* __restrict__ d, int n4) {
    int i = blockIdx.x * blockDim.x + threadIdx.x;
    if (i < n4) {
        float4 v = ((const float4*)s)[i];
        ushort4 o = { f2bf(v.x), f2bf(v.y), f2bf(v.z), f2bf(v.w) };
        ((ushort4*)d)[i] = o;
    }
}

// ---------------- embedding gather (with teacher-forcing shift) + cast ----------------
__global__ void k_embed(const int* __restrict__ inp, const float* __restrict__ emb,
                        u16* __restrict__ x) {
    int row = blockIdx.x;            // t*32 + b
    int t = row >> 5, b = row & 31;
    int st = (t == 0) ? 0 : (t - 1);
    int idx = inp[st * BB + b];
    int e = threadIdx.x * 4;         // 128 threads * 4 = 512
    float4 v = *(const float4*)(emb + (size_t)idx * EE + e);
    ushort4 o = { f2bf(v.x), f2bf(v.y), f2bf(v.z), f2bf(v.w) };
    *(ushort4*)(x + (size_t)row * EE + e) = o;
}

// ---------------- bf16 GEMM, C[M,N] = A[M,K] * B[N,K]^T + bias[N] ----------------
// m97 structure: 128x128 tile, BK=32, 256 threads = 4 waves (2x2 of 64x64),
// global_load_lds width 16 staging, 16x16x32 bf16 MFMA.
__global__ __launch_bounds__(256) void k_gemm_bt(
    const u16* __restrict__ A, const u16* __restrict__ B,
    const float* __restrict__ bias, float* __restrict__ C,
    int M, int N, int K)
{
    __shared__ u16 As[128 * 32];
    __shared__ u16 Bs[128 * 32];
    const int tid  = threadIdx.x;
    const int wave = tid >> 6;
    const int lane = tid & 63;
    const int m0 = blockIdx.y * 128;
    const int n0 = blockIdx.x * 128;
    const int wm = wave & 1;          // M half
    const int wn = wave >> 1;         // N half

    f32x4 acc[4][4];
    #pragma unroll
    for (int i = 0; i < 4; ++i)
        #pragma unroll
        for (int j = 0; j < 4; ++j) {
            f32x4 z = {0.f, 0.f, 0.f, 0.f};
            acc[i][j] = z;
        }

    const int srow = tid >> 2;         // staging row within 64-row half
    const int scol = (tid & 3) * 8;    // staging col (bf16 elems)
    const int mrow = wm * 64 + (lane & 15);
    const int nrow = wn * 64 + (lane & 15);
    const int kq   = (lane >> 4) * 8;

    for (int k0 = 0; k0 < K; k0 += 32) {
        __syncthreads();
        #pragma unroll
        for (int i = 0; i < 2; ++i) {
            int row = i * 64 + srow;
            gld_lds16(A + (size_t)(m0 + row) * K + k0 + scol,
                      As + (size_t)(i * 256 + wave * 64) * 8);
            gld_lds16(B + (size_t)(n0 + row) * K + k0 + scol,
                      Bs + (size_t)(i * 256 + wave * 64) * 8);
        }
        __syncthreads();

        bf16x8 a[4], b[4];
        #pragma unroll
        for (int x = 0; x < 4; ++x) {
            a[x] = *(const bf16x8*)&As[(mrow + x * 16) * 32 + kq];
            b[x] = *(const bf16x8*)&Bs[(nrow + x * 16) * 32 + kq];
        }
        #pragma unroll
        for (int mi = 0; mi < 4; ++mi)
            #pragma unroll
            for (int ni = 0; ni < 4; ++ni)
                acc[mi][ni] = __builtin_amdgcn_mfma_f32_16x16x32_bf16(
                    a[mi], b[ni], acc[mi][ni], 0, 0, 0);
    }

    // epilogue: C/D layout col = lane&15, row = (lane>>4)*4 + reg
    const int rbase = m0 + wm * 64 + (lane >> 4) * 4;
    const int cbase = n0 + wn * 64 + (lane & 15);
    #pragma unroll
    for (int mi = 0; mi < 4; ++mi) {
        #pragma unroll
        for (int ni = 0; ni < 4; ++ni) {
            int c = cbase + ni * 16;
            float bv = bias[c];
            int r0 = rbase + mi * 16;
            #pragma unroll
            for (int rr = 0; rr < 4; ++rr)
                C[(size_t)(r0 + rr) * N + c] = acc[mi][ni][rr] + bv;
        }
    }
}

// ---------------- persistent GRU scan (cooperative) ----------------
// 64 blocks x 192 threads (3 waves = gates r/z/n). Block owns 16 h-columns.
// w_hh rows for this block live in LDS for the whole scan (cast fp32->bf16 once).
// fp32 h state for the block's 16 columns stays in LDS; bf16 h goes to hseq[t]
// (needed globally by the next step's K-loop and by the logits GEMM).
// 127 grid.sync()s replace 128 kernel launches.
__global__ __launch_bounds__(192) void k_gru_scan(
    const float* __restrict__ gx,   // [T, 32, 3H] fp32
    const u16*   __restrict__ hz,   // [32, H] zeros (bf16)
    const float* __restrict__ whh,  // [3H, H] fp32
    const float* __restrict__ bhh,  // [3H]
    u16*   __restrict__ hseq,       // [T, 32, H] bf16 out
    float* __restrict__ hfin)       // [32, H] fp32 final hidden (into d_out tail)
{
    // row stride 1032 elems = 2064 B = odd multiple of 16 B -> the 64-lane
    // ds_read_b128 spreads evenly over all 8 16B LDS slots (conflict-free).
    __shared__ u16   wl[48][1032];
    __shared__ float gh[3][2][16][16];
    __shared__ float hf[32][16];

    cg::grid_group grid = cg::this_grid();
    const int tid  = threadIdx.x;
    const int wave = tid >> 6;           // gate: 0=r, 1=z, 2=n
    const int lane = tid & 63;
    const int j0   = blockIdx.x * 16;
    const int c16  = lane & 15;
    const int kq   = (lane >> 4) * 8;

    // ---- one-time: stage this block's 48 w_hh rows into LDS (fp32 -> bf16) ----
    for (int i = tid; i < 48 * 128; i += 192) {
        int lr = i >> 7;                 // local row 0..47 (gate*16 + col)
        int e8 = (i & 127) << 3;         // elem offset 0..1016 step 8
        const float* src = whh + (size_t)((lr >> 4) * HH + j0 + (lr & 15)) * HH + e8;
        float4 v0 = *(const float4*)src;
        float4 v1 = *(const float4*)(src + 4);
        bf16x8 o;
        o[0] = (short)f2bf(v0.x); o[1] = (short)f2bf(v0.y);
        o[2] = (short)f2bf(v0.z); o[3] = (short)f2bf(v0.w);
        o[4] = (short)f2bf(v1.x); o[5] = (short)f2bf(v1.y);
        o[6] = (short)f2bf(v1.z); o[7] = (short)f2bf(v1.w);
        *(bf16x8*)&wl[lr][e8] = o;
    }
    // ---- init fp32 h state ----
    for (int i = tid; i < 512; i += 192) hf[i >> 4][i & 15] = 0.f;
    // ---- per-thread bias registers (constant across steps) ----
    float br_[3], bz_[3], bn_[3];
    #pragma unroll
    for (int i = 0; i < 3; ++i) {
        int e = tid + 192 * i;
        if (e < 512) {
            int j = j0 + (e & 15);
            br_[i] = bhh[j]; bz_[i] = bhh[HH + j]; bn_[i] = bhh[2 * HH + j];
        }
    }
    __syncthreads();

    const u16* hprev = hz;
    const int wrow = wave * 16 + c16;
    for (int t = 0; t < TT; ++t) {
        // prefetch this step's gx values early (L3 latency hides under K-loop)
        float gr_[3], gz_[3], gn_[3];
        const float* gxt = gx + (size_t)t * (BB * 3 * HH);
        #pragma unroll
        for (int i = 0; i < 3; ++i) {
            int e = tid + 192 * i;
            if (e < 512) {
                const float* g = gxt + (size_t)(e >> 4) * (3 * HH) + j0 + (e & 15);
                gr_[i] = g[0]; gz_[i] = g[HH]; gn_[i] = g[2 * HH];
            }
        }
        // ---- gh = hprev @ whh_block^T (per-gate wave, 2 MFMA chains) ----
        f32x4 acc0 = {0.f, 0.f, 0.f, 0.f};
        f32x4 acc1 = {0.f, 0.f, 0.f, 0.f};
        const u16* a0p = hprev + (size_t)c16 * HH + kq;
        const u16* a1p = a0p + (size_t)16 * HH;
        const u16* blp = &wl[wrow][kq];
        for (int kk = 0; kk < HH; kk += 32) {
            bf16x8 b  = *(const bf16x8*)(blp + kk);
            bf16x8 a0 = *(const bf16x8*)(a0p + kk);
            bf16x8 a1 = *(const bf16x8*)(a1p + kk);
            acc0 = __builtin_amdgcn_mfma_f32_16x16x32_bf16(a0, b, acc0, 0, 0, 0);
            acc1 = __builtin_amdgcn_mfma_f32_16x16x32_bf16(a1, b, acc1, 0, 0, 0);
        }
        #pragma unroll
        for (int rr = 0; rr < 4; ++rr) {
            gh[wave][0][(lane >> 4) * 4 + rr][c16] = acc0[rr];
            gh[wave][1][(lane >> 4) * 4 + rr][c16] = acc1[rr];
        }
        __syncthreads();
        // ---- gates + h update (elementwise over block's 32x16 slice) ----
        u16* hout = hseq + (size_t)t * BB * HH;
        #pragma unroll
        for (int i = 0; i < 3; ++i) {
            int e = tid + 192 * i;
            if (e < 512) {
                int row = e >> 4, col = e & 15;
                float hr  = gh[0][row >> 4][row & 15][col] + br_[i];
                float hz_ = gh[1][row >> 4][row & 15][col] + bz_[i];
                float hn  = gh[2][row >> 4][row & 15][col] + bn_[i];
                float r = 1.f / (1.f + expf(-(gr_[i] + hr)));
                float z = 1.f / (1.f + expf(-(gz_[i] + hz_)));
                float n = tanhf(gn_[i] + r * hn);
                float hnew = (1.f - z) * n + z * hf[row][col];
                hf[row][col] = hnew;
                hout[(size_t)row * HH + j0 + col] = f2bf(hnew);
            }
        }
        hprev = hout;
        if (t != TT - 1) grid.sync();   // publish hseq[t] to all blocks
    }
    // ---- final fp32 hidden state (same thread->elem mapping as gates) ----
    for (int i = tid; i < 512; i += 192) {
        int row = i >> 4, col = i & 15;
        hfin[(size_t)row * HH + j0 + col] = hf[row][col];
    }
}

extern "C" void kernel_launch(void* const* d_in, const int* in_sizes, int n_in,
                              void* d_out, int out_size, void* d_ws, size_t ws_size,
                              hipStream_t stream) {
    const int*   inputs = (const int*)d_in[0];
    // d_in[1] encoder_output, d_in[2] encoder_mask: unused by reference
    const float* emb    = (const float*)d_in[3];
    const float* w_ih   = (const float*)d_in[4];
    const float* w_hh   = (const float*)d_in[5];
    const float* b_ih   = (const float*)d_in[6];
    const float* b_hh   = (const float*)d_in[7];
    const float* out_w  = (const float*)d_in[8];
    const float* out_b  = (const float*)d_in[9];
    float* out = (float*)d_out;

    char* ws = (char*)d_ws;
    // workspace layout (bytes) — whh_bf / h0 / h1 slots now unused (scan kernel
    // casts w_hh fp32->bf16 while staging into LDS, fp32 h lives in LDS).
    u16*   wih_bf  = (u16*)  (ws + 0);          //  3,145,728
    u16*   outw_bf = (u16*)  (ws + 9437184);    // 65,536,000
    u16*   x_bf    = (u16*)  (ws + 74973184);   //  4,194,304
    float* gx      = (float*)(ws + 79167488);   // 50,331,648
    u16*   hseq    = (u16*)  (ws + 129499136);  //  8,388,608
    u16*   hz_bf   = (u16*)  (ws + 137887744);  //     65,536

    // 1) casts to bf16 (w_hh cast is folded into the scan kernel's LDS staging)
    k_cast<<<1536,  256, 0, stream>>>(w_ih,  wih_bf,  (3*HH*EE)/4);
    k_cast<<<32000, 256, 0, stream>>>(out_w, outw_bf, ((size_t)VV*HH)/4);
    // 2) embedding gather (shifted) + cast
    k_embed<<<TT*BB, 128, 0, stream>>>(inputs, emb, x_bf);
    // 3) gx = x @ w_ih^T + b_ih   [4096, 3072]
    {
        dim3 g(3*HH/128, (TT*BB)/128);
        k_gemm_bt<<<g, 256, 0, stream>>>(x_bf, wih_bf, b_ih, gx, TT*BB, 3*HH, EE);
    }
    // 4) zero h_{-1}
    hipMemsetAsync(hz_bf, 0, BB*HH*sizeof(u16), stream);
    // 5) persistent GRU scan: one cooperative launch, grid.sync between steps
    {
        const float* gxp  = gx;
        const u16*   hzp  = hz_bf;
        const float* whhp = w_hh;
        const float* bhhp = b_hh;
        u16*         hsp  = hseq;
        float*       hfp  = out + (size_t)TT * BB * VV;
        void* args[] = { (void*)&gxp, (void*)&hzp, (void*)&whhp,
                         (void*)&bhhp, (void*)&hsp, (void*)&hfp };
        hipLaunchCooperativeKernel((const void*)k_gru_scan, dim3(64), dim3(192),
                                   args, 0, stream);
    }
    // 6) logits = outputs @ out_w^T + out_b   [4096, 32000] -> d_out
    {
        dim3 g(VV/128, (TT*BB)/128);
        k_gemm_bt<<<g, 256, 0, stream>>>(hseq, outw_bf, out_b, out, TT*BB, VV, HH);
    }
    // 7) final hidden state already written directly by k_gru_scan
}

// Round 2
// 2258.080 us; speedup vs baseline: 1.3135x; 1.3135x over previous
//
#include <hip/hip_runtime.h>
#include <hip/hip_bf16.h>
#include <stdint.h>

#define TT 128
#define BB 32
#define EE 512
#define HH 1024
#define VV 32000

typedef unsigned short u16;
typedef short bf16x8 __attribute__((ext_vector_type(8)));
typedef float f32x4 __attribute__((ext_vector_type(4)));

__device__ __forceinline__ u16 f2bf(float f) {
    unsigned int u = __builtin_bit_cast(unsigned int, f);
    u = (u + 0x7fffu + ((u >> 16) & 1u)) >> 16;
    return (u16)u;
}

__device__ __forceinline__ void gld_lds16(const u16* g, u16* l) {
    __builtin_amdgcn_global_load_lds(
        (__attribute__((address_space(1))) void*)g,
        (__attribute__((address_space(3))) void*)l, 16, 0, 0);
}

// ---------------- fp32 -> bf16 cast, 4 elems/thread ----------------
__global__ void k_cast(const float* __restrict__ s, u16* __restrict__ d, int n4) {
    int i = blockIdx.x * blockDim.x + threadIdx.x;
    if (i < n4) {
        float4 v = ((const float4*)s)[i];
        ushort4 o = { f2bf(v.x), f2bf(v.y), f2bf(v.z), f2bf(v.w) };
        ((ushort4*)d)[i] = o;
    }
}

// ---------------- embedding gather (with teacher-forcing shift) + cast ----------------
__global__ void k_embed(const int* __restrict__ inp, const float* __restrict__ emb,
                        u16* __restrict__ x) {
    int row = blockIdx.x;            // t*32 + b
    int t = row >> 5, b = row & 31;
    int st = (t == 0) ? 0 : (t - 1);
    int idx = inp[st * BB + b];
    int e = threadIdx.x * 4;         // 128 threads * 4 = 512
    float4 v = *(const float4*)(emb + (size_t)idx * EE + e);
    ushort4 o = { f2bf(v.x), f2bf(v.y), f2bf(v.z), f2bf(v.w) };
    *(ushort4*)(x + (size_t)row * EE + e) = o;
}

// ---------------- bf16 GEMM, C[M,N] = A[M,K] * B[N,K]^T + bias[N] ----------------
// m97 structure: 128x128 tile, BK=32, 256 threads = 4 waves (2x2 of 64x64),
// global_load_lds width 16 staging, 16x16x32 bf16 MFMA.
__global__ __launch_bounds__(256) void k_gemm_bt(
    const u16* __restrict__ A, const u16* __restrict__ B,
    const float* __restrict__ bias, float* __restrict__ C,
    int M, int N, int K)
{
    __shared__ u16 As[128 * 32];
    __shared__ u16 Bs[128 * 32];
    const int tid  = threadIdx.x;
    const int wave = tid >> 6;
    const int lane = tid & 63;
    const int m0 = blockIdx.y * 128;
    const int n0 = blockIdx.x * 128;
    const int wm = wave & 1;          // M half
    const int wn = wave >> 1;         // N half

    f32x4 acc[4][4];
    #pragma unroll
    for (int i = 0; i < 4; ++i)
        #pragma unroll
        for (int j = 0; j < 4; ++j) {
            f32x4 z = {0.f, 0.f, 0.f, 0.f};
            acc[i][j] = z;
        }

    const int srow = tid >> 2;         // staging row within 64-row half
    const int scol = (tid & 3) * 8;    // staging col (bf16 elems)
    const int mrow = wm * 64 + (lane & 15);
    const int nrow = wn * 64 + (lane & 15);
    const int kq   = (lane >> 4) * 8;

    for (int k0 = 0; k0 < K; k0 += 32) {
        __syncthreads();
        #pragma unroll
        for (int i = 0; i < 2; ++i) {
            int row = i * 64 + srow;
            gld_lds16(A + (size_t)(m0 + row) * K + k0 + scol,
                      As + (size_t)(i * 256 + wave * 64) * 8);
            gld_lds16(B + (size_t)(n0 + row) * K + k0 + scol,
                      Bs + (size_t)(i * 256 + wave * 64) * 8);
        }
        __syncthreads();

        bf16x8 a[4], b[4];
        #pragma unroll
        for (int x = 0; x < 4; ++x) {
            a[x] = *(const bf16x8*)&As[(mrow + x * 16) * 32 + kq];
            b[x] = *(const bf16x8*)&Bs[(nrow + x * 16) * 32 + kq];
        }
        #pragma unroll
        for (int mi = 0; mi < 4; ++mi)
            #pragma unroll
            for (int ni = 0; ni < 4; ++ni)
                acc[mi][ni] = __builtin_amdgcn_mfma_f32_16x16x32_bf16(
                    a[mi], b[ni], acc[mi][ni], 0, 0, 0);
    }

    // epilogue: C/D layout col = lane&15, row = (lane>>4)*4 + reg
    const int rbase = m0 + wm * 64 + (lane >> 4) * 4;
    const int cbase = n0 + wn * 64 + (lane & 15);
    #pragma unroll
    for (int mi = 0; mi < 4; ++mi) {
        #pragma unroll
        for (int ni = 0; ni < 4; ++ni) {
            int c = cbase + ni * 16;
            float bv = bias[c];
            int r0 = rbase + mi * 16;
            #pragma unroll
            for (int rr = 0; rr < 4; ++rr)
                C[(size_t)(r0 + rr) * N + c] = acc[mi][ni][rr] + bv;
        }
    }
}

// ---------------- persistent GRU scan, hand-rolled device barrier ----------------
// 64 blocks x 384 threads (6 waves). Block owns 16 h-columns.
//   waves 0-2: gates r/z/n over K in [0,512)
//   waves 3-5: gates r/z/n over K in [512,1024)
// w_hh rows for this block live in LDS for the whole scan (cast fp32->bf16 once).
// fp32 h state for the block's 16 columns stays in LDS; bf16 h goes to hseq[t].
// Barrier: per-block flag cacheline + one wave spin-loading all 64 flags in
// parallel; __threadfence (agent release/acquire) handles cross-XCD visibility.
// Plain launch: 64 blocks, 1 block/CU (LDS-limited) on 256 CUs -> co-resident.
__global__ __launch_bounds__(384, 1) void k_gru_scan(
    const float* __restrict__ gx,   // [T, 32, 3H] fp32
    const float* __restrict__ whh,  // [3H, H] fp32
    const float* __restrict__ bhh,  // [3H]
    u16*   __restrict__ hseq,       // [T, 32, H] bf16 out
    float* __restrict__ hfin,       // [32, H] fp32 final hidden (d_out tail)
    unsigned* __restrict__ flags)   // [64 * 32] u32, zeroed, 128B/block stride
{
    // row stride 1032 elems = 2064 B = odd multiple of 16 B -> the wave's 64
    // ds_read_b128 spread evenly over all 8 16B LDS slots (no extra cost).
    __shared__ u16   wl[48][1032];
    __shared__ float gh[2][3][2][16][17];   // [khalf][gate][mtile][row][col+pad]
    __shared__ float hf[32][16];

    const int tid  = threadIdx.x;
    const int wave = tid >> 6;
    const int gate = (wave < 3) ? wave : wave - 3;   // 0=r 1=z 2=n
    const int kh   = (wave < 3) ? 0 : 1;
    const int lane = tid & 63;
    const int j0   = blockIdx.x * 16;
    const int c16  = lane & 15;
    const int kq   = (lane >> 4) * 8;
    const int bx   = blockIdx.x;

    // ---- one-time: stage this block's 48 w_hh rows into LDS (fp32 -> bf16) ----
    for (int i = tid; i < 48 * 128; i += 384) {
        int lr = i >> 7;                 // local row 0..47 (gate*16 + col)
        int e8 = (i & 127) << 3;         // elem offset 0..1016 step 8
        const float* src = whh + (size_t)((lr >> 4) * HH + j0 + (lr & 15)) * HH + e8;
        float4 v0 = *(const float4*)src;
        float4 v1 = *(const float4*)(src + 4);
        bf16x8 o;
        o[0] = (short)f2bf(v0.x); o[1] = (short)f2bf(v0.y);
        o[2] = (short)f2bf(v0.z); o[3] = (short)f2bf(v0.w);
        o[4] = (short)f2bf(v1.x); o[5] = (short)f2bf(v1.y);
        o[6] = (short)f2bf(v1.z); o[7] = (short)f2bf(v1.w);
        *(bf16x8*)&wl[lr][e8] = o;
    }
    // ---- init fp32 h state ----
    for (int i = tid; i < 512; i += 384) hf[i >> 4][i & 15] = 0.f;
    // ---- per-thread bias registers (constant across steps) ----
    float br_[2], bz_[2], bn_[2];
    #pragma unroll
    for (int i = 0; i < 2; ++i) {
        int e = tid + 384 * i;
        if (e < 512) {
            int j = j0 + (e & 15);
            br_[i] = bhh[j]; bz_[i] = bhh[HH + j]; bn_[i] = bhh[2 * HH + j];
        }
    }
    // ---- prefetch gx for t = 0 ----
    float gr_[2], gz_[2], gn_[2];
    #pragma unroll
    for (int i = 0; i < 2; ++i) {
        int e = tid + 384 * i;
        if (e < 512) {
            const float* g = gx + (size_t)(e >> 4) * (3 * HH) + j0 + (e & 15);
            gr_[i] = g[0]; gz_[i] = g[HH]; gn_[i] = g[2 * HH];
        }
    }
    __syncthreads();

    const int wrow  = gate * 16 + c16;
    const int kbase = kh * 512;
    for (int t = 0; t < TT; ++t) {
        // ---- gh partial = hprev[:, kh-half] @ whh_block^T for this gate ----
        f32x4 acc0 = {0.f, 0.f, 0.f, 0.f};
        f32x4 acc1 = {0.f, 0.f, 0.f, 0.f};
        if (t > 0) {
            const u16* hprev = hseq + (size_t)(t - 1) * BB * HH;
            const u16* a0p = hprev + (size_t)c16 * HH + kbase + kq;
            const u16* a1p = a0p + (size_t)16 * HH;
            const u16* blp = &wl[wrow][kbase + kq];
            #pragma unroll 4
            for (int kk = 0; kk < 512; kk += 32) {
                bf16x8 b  = *(const bf16x8*)(blp + kk);
                bf16x8 a0 = *(const bf16x8*)(a0p + kk);
                bf16x8 a1 = *(const bf16x8*)(a1p + kk);
                acc0 = __builtin_amdgcn_mfma_f32_16x16x32_bf16(a0, b, acc0, 0, 0, 0);
                acc1 = __builtin_amdgcn_mfma_f32_16x16x32_bf16(a1, b, acc1, 0, 0, 0);
            }
        }
        #pragma unroll
        for (int rr = 0; rr < 4; ++rr) {
            gh[kh][gate][0][(lane >> 4) * 4 + rr][c16] = acc0[rr];
            gh[kh][gate][1][(lane >> 4) * 4 + rr][c16] = acc1[rr];
        }
        __syncthreads();
        // ---- gates + h update (elementwise over block's 32x16 slice) ----
        u16* hout = hseq + (size_t)t * BB * HH;
        #pragma unroll
        for (int i = 0; i < 2; ++i) {
            int e = tid + 384 * i;
            if (e < 512) {
                int row = e >> 4, col = e & 15;
                int m = row >> 4, rl = row & 15;
                float hr  = gh[0][0][m][rl][col] + gh[1][0][m][rl][col] + br_[i];
                float hz_ = gh[0][1][m][rl][col] + gh[1][1][m][rl][col] + bz_[i];
                float hn  = gh[0][2][m][rl][col] + gh[1][2][m][rl][col] + bn_[i];
                float r = 1.f / (1.f + expf(-(gr_[i] + hr)));
                float z = 1.f / (1.f + expf(-(gz_[i] + hz_)));
                float n = tanhf(gn_[i] + r * hn);
                float hnew = (1.f - z) * n + z * hf[row][col];
                hf[row][col] = hnew;
                hout[(size_t)row * HH + j0 + col] = f2bf(hnew);
            }
        }
        if (t != TT - 1) {
            // prefetch next step's gx: latency hides under the barrier spin
            const float* gxt = gx + (size_t)(t + 1) * (BB * 3 * HH);
            #pragma unroll
            for (int i = 0; i < 2; ++i) {
                int e = tid + 384 * i;
                if (e < 512) {
                    const float* g = gxt + (size_t)(e >> 4) * (3 * HH) + j0 + (e & 15);
                    gr_[i] = g[0]; gz_[i] = g[HH]; gn_[i] = g[2 * HH];
                }
            }
            // ---- device-wide barrier ----
            __syncthreads();                 // drains this block's stores (vmcnt 0)
            if (wave == 0) {
                __threadfence();             // agent release: flush dirty h to L3
                if (lane == 0)
                    __hip_atomic_store(&flags[bx * 32], (unsigned)(t + 1),
                                       __ATOMIC_RELAXED, __HIP_MEMORY_SCOPE_AGENT);
                unsigned v;
                do {
                    v = __hip_atomic_load(&flags[lane * 32],
                                          __ATOMIC_RELAXED, __HIP_MEMORY_SCOPE_AGENT);
                } while (__any(v < (unsigned)(t + 1)));
                __threadfence();             // agent acquire: kill stale lines
            }
            __syncthreads();
        }
    }
    // ---- final fp32 hidden state ----
    for (int i = tid; i < 512; i += 384) {
        hfin[(size_t)(i >> 4) * HH + j0 + (i & 15)] = hf[i >> 4][i & 15];
    }
}

extern "C" void kernel_launch(void* const* d_in, const int* in_sizes, int n_in,
                              void* d_out, int out_size, void* d_ws, size_t ws_size,
                              hipStream_t stream) {
    const int*   inputs = (const int*)d_in[0];
    // d_in[1] encoder_output, d_in[2] encoder_mask: unused by reference
    const float* emb    = (const float*)d_in[3];
    const float* w_ih   = (const float*)d_in[4];
    const float* w_hh   = (const float*)d_in[5];
    const float* b_ih   = (const float*)d_in[6];
    const float* b_hh   = (const float*)d_in[7];
    const float* out_w  = (const float*)d_in[8];
    const float* out_b  = (const float*)d_in[9];
    float* out = (float*)d_out;

    char* ws = (char*)d_ws;
    // workspace layout (bytes)
    u16*      wih_bf  = (u16*)     (ws + 0);          //  3,145,728
    u16*      outw_bf = (u16*)     (ws + 9437184);    // 65,536,000
    u16*      x_bf    = (u16*)     (ws + 74973184);   //  4,194,304
    float*    gx      = (float*)   (ws + 79167488);   // 50,331,648
    u16*      hseq    = (u16*)     (ws + 129499136);  //  8,388,608
    unsigned* flags   = (unsigned*)(ws + 137887744);  //      8,192

    // 1) casts to bf16 (w_hh cast is folded into the scan kernel's LDS staging)
    k_cast<<<1536,  256, 0, stream>>>(w_ih,  wih_bf,  (3*HH*EE)/4);
    k_cast<<<32000, 256, 0, stream>>>(out_w, outw_bf, ((size_t)VV*HH)/4);
    // 2) embedding gather (shifted) + cast
    k_embed<<<TT*BB, 128, 0, stream>>>(inputs, emb, x_bf);
    // 3) gx = x @ w_ih^T + b_ih   [4096, 3072]
    {
        dim3 g(3*HH/128, (TT*BB)/128);
        k_gemm_bt<<<g, 256, 0, stream>>>(x_bf, wih_bf, b_ih, gx, TT*BB, 3*HH, EE);
    }
    // 4) zero barrier flags
    hipMemsetAsync(flags, 0, 64 * 32 * sizeof(unsigned), stream);
    // 5) persistent GRU scan: one plain launch, hand-rolled barrier between steps
    k_gru_scan<<<64, 384, 0, stream>>>(gx, w_hh, b_hh, hseq,
                                       out + (size_t)TT * BB * VV, flags);
    // 6) logits = outputs @ out_w^T + out_b   [4096, 32000] -> d_out
    {
        dim3 g(VV/128, (TT*BB)/128);
        k_gemm_bt<<<g, 256, 0, stream>>>(hseq, outw_bf, out_b, out, TT*BB, VV, HH);
    }
    // 7) final hidden state already written directly by k_gru_scan
}